// Round 11
// baseline (4773.391 us; speedup 1.0000x reference)
//
#include <hip/hip_runtime.h>

#define TT 2048

typedef _Float16 f16;
typedef _Float16 f16x2 __attribute__((ext_vector_type(2)));
typedef _Float16 f16x8 __attribute__((ext_vector_type(8)));
typedef float f32x4 __attribute__((ext_vector_type(4)));
typedef unsigned int u32;

static __device__ __forceinline__ u32 cvtpk(float a, float b) {
  return __builtin_bit_cast(u32, __builtin_amdgcn_cvt_pkrtz(a, b));
}
static __device__ __forceinline__ f32x4 MF(f16x8 a, f16x8 b, f32x4 c) {
  return __builtin_amdgcn_mfma_f32_16x16x32_f16(a, b, c, 0, 0, 0);
}
// rcp(1 + exp2(x)) : with prescaled inputs this is sigmoid/tanh kernel.
static __device__ __forceinline__ float SG(float x) {
  return __builtin_amdgcn_rcpf(1.f + exp2f(x));
}
#define MEMBAR() asm volatile("" ::: "memory")
#define LGK0()   asm volatile("s_waitcnt lgkmcnt(0)" ::: "memory")

#define L2E 1.4426950408889634f
#define TWOL2E 2.8853900817779268f

// ============ K0: prep — weights -> prescaled f16 MFMA B-fragments ==========
// Gate mapping (16x16x32, B col n = lane&15):
//  L1: tile n=(q,j) q=0..3(i,f,g,o) j=0..3; gate = 64q + 4*ln + j; chunks c=0,1.
//  L2: tile n2=(q2,j2) j2=0..1; gate2 = 32q2 + 2*ln + j2.
// Rows for i,f,o scaled by -log2e (sigmoid via SG); g rows by +2log2e (tanh).
// ws layout (tiles of 512 f16): [0,32)=Wih1 (X wave), [32,64)=Whh1 (L1),
// [64,80)=Wih2, [80,88)=Whh2 (L2). Biases (scaled, f32) at +90112 B:
// b1f[16][16], then b2f[8][16].
__global__ void lstm2_v11_prep(const float* __restrict__ Wih1,
                               const float* __restrict__ Whh1,
                               const float* __restrict__ Wih2,
                               const float* __restrict__ Whh2,
                               const float* __restrict__ bih1,
                               const float* __restrict__ bhh1,
                               const float* __restrict__ bih2,
                               const float* __restrict__ bhh2,
                               f16* __restrict__ wsf,
                               float* __restrict__ wsb)
{
  const int T = blockIdx.x;
  const int L = threadIdx.x;
  if (T < 88) {
    const int ln = L & 15, lg = L >> 4;
    const float* src; int row, ld, k0, q;
    if (T < 64) {
      const int Tm = T & 31;
      q = Tm >> 3; const int j = (Tm >> 1) & 3, c = Tm & 1;
      row = 64 * q + 4 * ln + j; ld = 64; k0 = 32 * c + lg * 8;
      src = (T < 32) ? Wih1 : Whh1;
    } else if (T < 80) {
      const int Tm = T - 64;
      q = Tm >> 2; const int j2 = (Tm >> 1) & 1, c = Tm & 1;
      row = 32 * q + 2 * ln + j2; ld = 64; k0 = 32 * c + lg * 8;
      src = Wih2;
    } else {
      const int Tm = T - 80;
      q = Tm >> 1; const int j2 = Tm & 1;
      row = 32 * q + 2 * ln + j2; ld = 32; k0 = lg * 8;
      src = Whh2;
    }
    const float S = (q == 2) ? TWOL2E : -L2E;
    #pragma unroll
    for (int i = 0; i < 8; ++i)
      wsf[T * 512 + L * 8 + i] = (f16)(src[row * ld + k0 + i] * S);
  } else {
    for (int idx = L; idx < 384; idx += 64) {
      float v;
      if (idx < 256) {
        const int tile = idx >> 4, ln = idx & 15;
        const int q = tile >> 2, j = tile & 3;
        const int g = 64 * q + 4 * ln + j;
        v = (bih1[g] + bhh1[g]) * ((q == 2) ? TWOL2E : -L2E);
      } else {
        const int t2 = idx - 256;
        const int tile2 = t2 >> 4, ln = t2 & 15;
        const int q2 = tile2 >> 1, j2 = tile2 & 1;
        const int g = 32 * q2 + 2 * ln + j2;
        v = (bih2[g] + bhh2[g]) * ((q2 == 2) ? TWOL2E : -L2E);
      }
      wsb[idx] = v;
    }
  }
}

// ============ K1: main — single-wave serial chain per 16-row group ==========
struct Smem {
  float pre[4][16][64][4];  // x-proj ring (f32 D-frags), slot = t & 3  (64KB)
  f16 h1[8][16][72];        // h1 ring [slot][row][unit], slot = t & 7 (18KB)
  f16 h2[2][16][40];        // h2 double buffer                        (2.5KB)
  int fx, c1, c2, pad;
};

__launch_bounds__(192, 1)
__global__ void lstm2_v11_main(const float* __restrict__ x1,
                               const float* __restrict__ x2,
                               const f16* __restrict__ wsf,
                               const float* __restrict__ wsb,
                               float* __restrict__ out)
{
  extern __shared__ char smem_raw[];
  Smem* sm = (Smem*)smem_raw;

  const int tid = threadIdx.x;
  const int l = tid & 63;
  const int wid = tid >> 6;        // 0 = X producer, 1 = L1, 2 = L2
  const int ln = l & 15;
  const int lg = l >> 4;
  const int bid = blockIdx.x;      // 32 blocks
  const int which = bid >> 4;
  const int rowbase = (bid & 15) * 16;

  // zero h1[-1] (slot 7), h2[-1] (slot 1), flags
  for (int i = tid; i < 16 * 72; i += 192) ((f16*)sm->h1[7])[i] = (f16)0.f;
  for (int i = tid; i < 16 * 40; i += 192) ((f16*)sm->h2[1])[i] = (f16)0.f;
  if (tid == 0) { sm->fx = 0; sm->c1 = 0; sm->c2 = 0; }
  __syncthreads();   // only barrier

  volatile int* vfx = (volatile int*)&sm->fx;
  volatile int* vc1 = (volatile int*)&sm->c1;
  volatile int* vc2 = (volatile int*)&sm->c2;

  if (wid == 0) {
    // ================= X producer: pre[s] = x[s] @ Wih1^T + b1 (scaled) ====
    f16x8 w[32];
    #pragma unroll
    for (int i = 0; i < 32; ++i)
      w[i] = __builtin_bit_cast(f16x8, *(const uint4*)(wsf + i * 512 + l * 8));
    float bi[16];
    #pragma unroll
    for (int n = 0; n < 16; ++n) bi[n] = wsb[n * 16 + ln];

    const float* __restrict__ xr =
        (which ? x2 : x1) + (size_t)(rowbase + ln) * (TT * 64);
    float4 xA0, xA1, xA2, xA3, xB0, xB1, xB2, xB3;
    #define XLOAD(P0,P1,P2,P3,T_) { const float* ps = xr + (size_t)(T_) * 64; \
      P0 = *(const float4*)(ps + lg * 8);      P1 = *(const float4*)(ps + lg * 8 + 4); \
      P2 = *(const float4*)(ps + 32 + lg * 8); P3 = *(const float4*)(ps + 32 + lg * 8 + 4); }
    XLOAD(xA0,xA1,xA2,xA3, 0)
    XLOAD(xB0,xB1,xB2,xB3, 1)

    int lc1 = 0;
    #pragma unroll 1
    for (int s = 0; s < TT; s += 2) {
      if (lc1 < s - 2) {
        do { lc1 = *vc1; } while (lc1 < s - 2);
        MEMBAR();
      }
      // ---- step s (regs A) ----
      {
        uint4 u0 = {cvtpk(xA0.x,xA0.y), cvtpk(xA0.z,xA0.w),
                    cvtpk(xA1.x,xA1.y), cvtpk(xA1.z,xA1.w)};
        uint4 u1 = {cvtpk(xA2.x,xA2.y), cvtpk(xA2.z,xA2.w),
                    cvtpk(xA3.x,xA3.y), cvtpk(xA3.z,xA3.w)};
        const f16x8 xf0 = __builtin_bit_cast(f16x8, u0);
        const f16x8 xf1 = __builtin_bit_cast(f16x8, u1);
        const int tn = (s + 2 < TT) ? s + 2 : TT - 1;
        XLOAD(xA0,xA1,xA2,xA3, tn)          // prefetch next pair (1 pair lead)
        #pragma unroll
        for (int n = 0; n < 16; ++n) {
          f32x4 a = {bi[n], bi[n], bi[n], bi[n]};
          a = MF(xf0, w[2*n], a);
          a = MF(xf1, w[2*n+1], a);
          *(f32x4*)&sm->pre[s & 3][n][l][0] = a;
        }
        LGK0();
        if (l == 0) *vfx = s + 1;
      }
      // ---- step s+1 (regs B) ----
      {
        uint4 u0 = {cvtpk(xB0.x,xB0.y), cvtpk(xB0.z,xB0.w),
                    cvtpk(xB1.x,xB1.y), cvtpk(xB1.z,xB1.w)};
        uint4 u1 = {cvtpk(xB2.x,xB2.y), cvtpk(xB2.z,xB2.w),
                    cvtpk(xB3.x,xB3.y), cvtpk(xB3.z,xB3.w)};
        const f16x8 xf0 = __builtin_bit_cast(f16x8, u0);
        const f16x8 xf1 = __builtin_bit_cast(f16x8, u1);
        const int tn = (s + 3 < TT) ? s + 3 : TT - 1;
        XLOAD(xB0,xB1,xB2,xB3, tn)
        #pragma unroll
        for (int n = 0; n < 16; ++n) {
          f32x4 a = {bi[n], bi[n], bi[n], bi[n]};
          a = MF(xf0, w[2*n], a);
          a = MF(xf1, w[2*n+1], a);
          *(f32x4*)&sm->pre[(s + 1) & 3][n][l][0] = a;
        }
        LGK0();
        if (l == 0) *vfx = s + 2;
      }
    }
  } else if (wid == 1) {
    // ================= L1: whole recurrence intra-wave =====================
    f16x8 w[32];
    #pragma unroll
    for (int i = 0; i < 32; ++i)
      w[i] = __builtin_bit_cast(f16x8, *(const uint4*)(wsf + (32 + i) * 512 + l * 8));

    float cst[4][4];
    #pragma unroll
    for (int j = 0; j < 4; ++j)
      #pragma unroll
      for (int r = 0; r < 4; ++r) cst[j][r] = 0.f;

    int lfx = 0, lc2 = 0;
    #pragma unroll 1
    for (int t = 0; t < TT; ++t) {
      if (lfx < t + 1) {
        do { lfx = *vfx; } while (lfx < t + 1);
        MEMBAR();
      }
      // h1[t-1] A-fragments (same-wave LDS round trip, no sync needed)
      const f16x8 ha0 = *(const f16x8*)&sm->h1[(t - 1) & 7][ln][lg * 8];
      const f16x8 ha1 = *(const f16x8*)&sm->h1[(t - 1) & 7][ln][32 + lg * 8];
      f32x4 acc[16];
      #pragma unroll
      for (int n = 0; n < 16; ++n) acc[n] = *(const f32x4*)&sm->pre[t & 3][n][l][0];
      #pragma unroll
      for (int n = 0; n < 16; ++n) {
        acc[n] = MF(ha0, w[2*n], acc[n]);
        acc[n] = MF(ha1, w[2*n+1], acc[n]);
      }
      // back-pressure: overwriting h1 slot t&7 (= h1[t-8]); L2 must pass t-8
      if (lc2 < t - 7) {
        do { lc2 = *vc2; } while (lc2 < t - 7);
        MEMBAR();
      }
      // activations: unit u = 4*ln + j; i=acc[j], f=acc[4+j], g=acc[8+j], o=acc[12+j]
      float h[4][4];
      #pragma unroll
      for (int j = 0; j < 4; ++j) {
        #pragma unroll
        for (int r = 0; r < 4; ++r) {
          const float iv = SG(acc[j][r]);
          const float fv = SG(acc[4 + j][r]);
          const float gv = fmaf(-2.f, SG(acc[8 + j][r]), 1.f);
          const float ov = SG(acc[12 + j][r]);
          const float c = fmaf(fv, cst[j][r], iv * gv);
          cst[j][r] = c;
          const float th = fmaf(-2.f, SG(c * TWOL2E), 1.f);
          h[j][r] = ov * th;
        }
      }
      #pragma unroll
      for (int r = 0; r < 4; ++r) {
        const u32 lo = cvtpk(h[0][r], h[1][r]);
        const u32 hi = cvtpk(h[2][r], h[3][r]);
        *(uint2*)&sm->h1[t & 7][lg * 4 + r][4 * ln] = make_uint2(lo, hi);
      }
      LGK0();
      if (l == 0) *vc1 = t + 1;
    }
  } else {
    // ================= L2: one step behind off the h1 ring =================
    f16x8 wx[16];
    #pragma unroll
    for (int i = 0; i < 16; ++i)
      wx[i] = __builtin_bit_cast(f16x8, *(const uint4*)(wsf + (64 + i) * 512 + l * 8));
    f16x8 wh[8];
    #pragma unroll
    for (int i = 0; i < 8; ++i)
      wh[i] = __builtin_bit_cast(f16x8, *(const uint4*)(wsf + (80 + i) * 512 + l * 8));
    float b2[8];
    #pragma unroll
    for (int n = 0; n < 8; ++n) b2[n] = wsb[256 + n * 16 + ln];

    float cst[2][4];
    #pragma unroll
    for (int j = 0; j < 2; ++j)
      #pragma unroll
      for (int r = 0; r < 4; ++r) cst[j][r] = 0.f;

    int lc1 = 0;
    #pragma unroll 1
    for (int t = 0; t < TT; ++t) {
      if (lc1 < t + 1) {
        do { lc1 = *vc1; } while (lc1 < t + 1);
        MEMBAR();
      }
      const f16x8 ha0 = *(const f16x8*)&sm->h1[t & 7][ln][lg * 8];
      const f16x8 ha1 = *(const f16x8*)&sm->h1[t & 7][ln][32 + lg * 8];
      const f16x8 g0  = *(const f16x8*)&sm->h2[(t + 1) & 1][ln][lg * 8];
      f32x4 acc[8];
      #pragma unroll
      for (int n = 0; n < 8; ++n) {
        f32x4 a = {b2[n], b2[n], b2[n], b2[n]};
        a = MF(ha0, wx[2*n], a);
        a = MF(ha1, wx[2*n+1], a);
        a = MF(g0, wh[n], a);
        acc[n] = a;
      }
      float h2v[2][4];
      #pragma unroll
      for (int j = 0; j < 2; ++j) {
        #pragma unroll
        for (int r = 0; r < 4; ++r) {
          const float iv = SG(acc[j][r]);
          const float fv = SG(acc[2 + j][r]);
          const float gv = fmaf(-2.f, SG(acc[4 + j][r]), 1.f);
          const float ov = SG(acc[6 + j][r]);
          const float c = fmaf(fv, cst[j][r], iv * gv);
          cst[j][r] = c;
          const float th = fmaf(-2.f, SG(c * TWOL2E), 1.f);
          h2v[j][r] = ov * th;
        }
      }
      #pragma unroll
      for (int r = 0; r < 4; ++r)
        *(u32*)&sm->h2[t & 1][lg * 4 + r][2 * ln] = cvtpk(h2v[0][r], h2v[1][r]);
      LGK0();
      if (l == 0) *vc2 = t + 1;
      if (t == TT - 1) {
        #pragma unroll
        for (int r = 0; r < 4; ++r) {
          float2 o2 = make_float2(h2v[0][r], h2v[1][r]);
          *(float2*)&out[which * 8192 + (rowbase + lg * 4 + r) * 32 + 2 * ln] = o2;
        }
      }
    }
  }
}

extern "C" void kernel_launch(void* const* d_in, const int* in_sizes, int n_in,
                              void* d_out, int out_size, void* d_ws, size_t ws_size,
                              hipStream_t stream) {
  const float* x1   = (const float*)d_in[0];
  const float* x2   = (const float*)d_in[1];
  const float* Wih1 = (const float*)d_in[2];
  const float* Whh1 = (const float*)d_in[3];
  const float* bih1 = (const float*)d_in[4];
  const float* bhh1 = (const float*)d_in[5];
  const float* Wih2 = (const float*)d_in[6];
  const float* Whh2 = (const float*)d_in[7];
  const float* bih2 = (const float*)d_in[8];
  const float* bhh2 = (const float*)d_in[9];
  float* out = (float*)d_out;

  f16*   wsf = (f16*)d_ws;                        // 88 tiles * 1KB = 90112 B
  float* wsb = (float*)((char*)d_ws + 90112);     // 384 scaled biases

  (void)hipFuncSetAttribute((const void*)lstm2_v11_main,
                            hipFuncAttributeMaxDynamicSharedMemorySize,
                            (int)sizeof(Smem));

  lstm2_v11_prep<<<dim3(89), dim3(64), 0, stream>>>(
      Wih1, Whh1, Wih2, Whh2, bih1, bhh1, bih2, bhh2, wsf, wsb);
  lstm2_v11_main<<<dim3(32), dim3(192), sizeof(Smem), stream>>>(
      x1, x2, wsf, wsb, out);
}

// Round 12
// 2983.606 us; speedup vs baseline: 1.5999x; 1.5999x over previous
//
#include <hip/hip_runtime.h>

#define TT 2048

typedef _Float16 f16;
typedef _Float16 f16x8 __attribute__((ext_vector_type(8)));
typedef float f32x4 __attribute__((ext_vector_type(4)));
typedef unsigned int u32;

static __device__ __forceinline__ u32 cvtpk(float a, float b) {
  return __builtin_bit_cast(u32, __builtin_amdgcn_cvt_pkrtz(a, b));
}
static __device__ __forceinline__ f32x4 MF(f16x8 a, f16x8 b, f32x4 c) {
  return __builtin_amdgcn_mfma_f32_16x16x32_f16(a, b, c, 0, 0, 0);
}
// rcp(1 + exp2(x)): with prescaled weights this is sigmoid (and tanh via fma)
static __device__ __forceinline__ float SG(float x) {
  return __builtin_amdgcn_rcpf(1.f + exp2f(x));
}
#define L2E 1.4426950408889634f
#define TWOL2E 2.8853900817779268f

// asm-defined loads: the result is defined by the asm, so LLVM CANNOT
// rematerialize it by re-loading (the R3-R10 weight-reload pathology).
static __device__ __forceinline__ f16x8 ldfragA(const f16* p) {
  uint4 r;
  asm volatile("global_load_dwordx4 %0, %1, off\n\ts_waitcnt vmcnt(0)"
               : "=v"(r) : "v"(p) : "memory");
  return __builtin_bit_cast(f16x8, r);
}
static __device__ __forceinline__ float ldf32(const float* p) {
  float r;
  asm volatile("global_load_dword %0, %1, off\n\ts_waitcnt vmcnt(0)"
               : "=v"(r) : "v"(p) : "memory");
  return r;
}

// ============ K0: prep — weights -> prescaled f16 MFMA B-fragments ==========
// (verbatim from R11 — numerically validated, absmax 9.77e-4)
// L1 tile (q,j,c): T = 8q+2j+c (Wih1), +32 (Whh1); gate = 64q + 4*col + j.
// L2 tile: T = 64 + 4q2+2j2+c (Wih2), 80 + 2q2+j2 (Whh2); gate = 32q2+2*col+j2.
// i/f/o rows scaled by -log2e (sigmoid = SG); g rows by +2log2e (tanh via SG).
__global__ void lstm2_v12_prep(const float* __restrict__ Wih1,
                               const float* __restrict__ Whh1,
                               const float* __restrict__ Wih2,
                               const float* __restrict__ Whh2,
                               const float* __restrict__ bih1,
                               const float* __restrict__ bhh1,
                               const float* __restrict__ bih2,
                               const float* __restrict__ bhh2,
                               f16* __restrict__ wsf,
                               float* __restrict__ wsb)
{
  const int T = blockIdx.x;
  const int L = threadIdx.x;
  if (T < 88) {
    const int ln = L & 15, lg = L >> 4;
    const float* src; int row, ld, k0, q;
    if (T < 64) {
      const int Tm = T & 31;
      q = Tm >> 3; const int j = (Tm >> 1) & 3, c = Tm & 1;
      row = 64 * q + 4 * ln + j; ld = 64; k0 = 32 * c + lg * 8;
      src = (T < 32) ? Wih1 : Whh1;
    } else if (T < 80) {
      const int Tm = T - 64;
      q = Tm >> 2; const int j2 = (Tm >> 1) & 1, c = Tm & 1;
      row = 32 * q + 2 * ln + j2; ld = 64; k0 = 32 * c + lg * 8;
      src = Wih2;
    } else {
      const int Tm = T - 80;
      q = Tm >> 1; const int j2 = Tm & 1;
      row = 32 * q + 2 * ln + j2; ld = 32; k0 = lg * 8;
      src = Whh2;
    }
    const float S = (q == 2) ? TWOL2E : -L2E;
    #pragma unroll
    for (int i = 0; i < 8; ++i)
      wsf[T * 512 + L * 8 + i] = (f16)(src[row * ld + k0 + i] * S);
  } else {
    for (int idx = L; idx < 384; idx += 64) {
      float v;
      if (idx < 256) {
        const int tile = idx >> 4, ln = idx & 15;
        const int q = tile >> 2, j = tile & 3;
        const int g = 64 * q + 4 * ln + j;
        v = (bih1[g] + bhh1[g]) * ((q == 2) ? TWOL2E : -L2E);
      } else {
        const int t2 = idx - 256;
        const int tile2 = t2 >> 4, ln = t2 & 15;
        const int q2 = tile2 >> 1, j2 = tile2 & 1;
        const int g = 32 * q2 + 2 * ln + j2;
        v = (bih2[g] + bhh2[g]) * ((q2 == 2) ? TWOL2E : -L2E);
      }
      wsb[idx] = v;
    }
  }
}

// ============ K1: main — 4 HOMOGENEOUS waves, fused L1+L2+staging ==========
// Wave w (0..3): L1 unit-group j=w (units 4*col+w), 16 MFMA + 4 act/lane.
// Waves 0,1 additionally: L2 j2=w (units 2*col+w), 12 MFMA + 4 act/lane,
// one step behind. x staged by ALL 256 threads (1 float4 each / step,
// 8-step batches). One __syncthreads per step between identical waves.
__launch_bounds__(256, 1)
__global__ void lstm2_v12_main(const float* __restrict__ x1,
                               const float* __restrict__ x2,
                               const f16* __restrict__ wsf,
                               const float* __restrict__ wsb,
                               float* __restrict__ out)
{
  __shared__ __align__(16) u32 s_ring[16][512];   // x A-frag ring, slot=t&15
  __shared__ __align__(16) f16 s_h1[4][16][72];   // h1 ring [slot][row][unit]
  __shared__ __align__(16) f16 s_h2[2][16][40];   // h2 ring

  const int tid = threadIdx.x;
  const int l = tid & 63;
  const int w = tid >> 6;          // wave 0..3
  const int ln = l & 15;           // A-row / D-col index
  const int lg = l >> 4;           // k-group
  const int bid = blockIdx.x;      // 32 blocks
  const int which = bid >> 4;
  const int rowbase = (bid & 15) * 16;

  for (int i = tid; i < 16 * 72; i += 256) ((f16*)s_h1[3])[i] = (f16)0.f;
  for (int i = tid; i < 16 * 40; i += 256) ((f16*)s_h2[1])[i] = (f16)0.f;

  // ---- weight fragments: asm-pinned VGPR residents ----
  f16x8 wx1[4][2], wh1[4][2];
  float b1[4];
  #pragma unroll
  for (int q = 0; q < 4; ++q) {
    #pragma unroll
    for (int c = 0; c < 2; ++c) {
      wx1[q][c] = ldfragA(wsf + (8 * q + 2 * w + c) * 512 + l * 8);
      wh1[q][c] = ldfragA(wsf + (32 + 8 * q + 2 * w + c) * 512 + l * 8);
    }
    b1[q] = ldf32(wsb + (4 * q + w) * 16 + ln);
  }
  const int w2 = w & 1;   // waves 2,3 load (unused) copies — keeps waves identical
  f16x8 wx2[4][2], wh2[4];
  float b2[4];
  #pragma unroll
  for (int q = 0; q < 4; ++q) {
    #pragma unroll
    for (int c = 0; c < 2; ++c)
      wx2[q][c] = ldfragA(wsf + (64 + 4 * q + 2 * w2 + c) * 512 + l * 8);
    wh2[q] = ldfragA(wsf + (80 + 2 * q + w2) * 512 + l * 8);
    b2[q] = ldf32(wsb + 256 + (2 * q + w2) * 16 + ln);
  }

  // ---- x staging setup: thread stages (row, feat-quad) ----
  const int xrow = tid & 15;
  const int q4 = tid >> 4;                   // 0..15
  const int chunk = q4 >> 3, kg = (q4 >> 1) & 3, hh = q4 & 1;
  const float* __restrict__ xsrc =
      (which ? x2 : x1) + (size_t)(rowbase + xrow) * (TT * 64) + q4 * 4;
  const int ridx = chunk * 256 + kg * 64 + xrow * 4 + 2 * hh;

  float4 xb[8];
  #pragma unroll
  for (int p = 0; p < 8; ++p) xb[p] = *(const float4*)(xsrc + (size_t)p * 64);
  #pragma unroll
  for (int p = 0; p < 8; ++p) {
    *(uint2*)&s_ring[p][ridx] =
        make_uint2(cvtpk(xb[p].x, xb[p].y), cvtpk(xb[p].z, xb[p].w));
  }
  #pragma unroll
  for (int p = 0; p < 8; ++p)
    xb[p] = *(const float4*)(xsrc + (size_t)(8 + p) * 64);
  __syncthreads();

  float cc1[4] = {0.f, 0.f, 0.f, 0.f};
  float cc2[4] = {0.f, 0.f, 0.f, 0.f};

  #pragma unroll 1
  for (int i = 0; i <= TT; ++i) {
    if ((i & 7) == 0) {
      // commit steps i+8..i+15 (loads issued last superstep), issue i+16..+23
      #pragma unroll
      for (int p = 0; p < 8; ++p) {
        *(uint2*)&s_ring[(i + 8 + p) & 15][ridx] =
            make_uint2(cvtpk(xb[p].x, xb[p].y), cvtpk(xb[p].z, xb[p].w));
      }
      #pragma unroll
      for (int p = 0; p < 8; ++p) {
        int s = i + 16 + p; if (s > TT - 1) s = TT - 1;
        xb[p] = *(const float4*)(xsrc + (size_t)s * 64);
      }
    }
    // ---- L1 step i (all 4 waves, unit-group j=w) ----
    if (i < TT) {
      const u32* rs = s_ring[i & 15];
      const f16x8 xa0 = *(const f16x8*)&rs[lg * 64 + ln * 4];
      const f16x8 xa1 = *(const f16x8*)&rs[256 + lg * 64 + ln * 4];
      const f16* hb = &s_h1[(i + 3) & 3][ln][lg * 8];   // h1[i-1]
      const f16x8 ha0 = *(const f16x8*)hb;
      const f16x8 ha1 = *(const f16x8*)(hb + 32);
      f32x4 acc[4];
      #pragma unroll
      for (int q = 0; q < 4; ++q) {
        f32x4 a = {b1[q], b1[q], b1[q], b1[q]};
        a = MF(xa0, wx1[q][0], a);
        a = MF(xa1, wx1[q][1], a);
        a = MF(ha0, wh1[q][0], a);
        a = MF(ha1, wh1[q][1], a);
        acc[q] = a;
      }
      #pragma unroll
      for (int r = 0; r < 4; ++r) {
        const float iv = SG(acc[0][r]);
        const float fv = SG(acc[1][r]);
        const float gv = fmaf(-2.f, SG(acc[2][r]), 1.f);
        const float ov = SG(acc[3][r]);
        const float c = fmaf(fv, cc1[r], iv * gv);
        cc1[r] = c;
        const float th = fmaf(-2.f, SG(c * TWOL2E), 1.f);
        s_h1[i & 3][lg * 4 + r][4 * ln + w] = (f16)(ov * th);
      }
    }
    // ---- L2 step t=i-1 (waves 0,1 only, unit-group j2=w) ----
    if (w < 2 && i >= 1) {
      const int t = i - 1;
      const f16* hb = &s_h1[t & 3][ln][lg * 8];          // h1[t]
      const f16x8 ha0 = *(const f16x8*)hb;
      const f16x8 ha1 = *(const f16x8*)(hb + 32);
      const f16x8 g0 = *(const f16x8*)&s_h2[(t + 1) & 1][ln][lg * 8]; // h2[t-1]
      f32x4 acc2[4];
      #pragma unroll
      for (int q = 0; q < 4; ++q) {
        f32x4 a = {b2[q], b2[q], b2[q], b2[q]};
        a = MF(ha0, wx2[q][0], a);
        a = MF(ha1, wx2[q][1], a);
        a = MF(g0, wh2[q], a);
        acc2[q] = a;
      }
      #pragma unroll
      for (int r = 0; r < 4; ++r) {
        const float iv = SG(acc2[0][r]);
        const float fv = SG(acc2[1][r]);
        const float gv = fmaf(-2.f, SG(acc2[2][r]), 1.f);
        const float ov = SG(acc2[3][r]);
        const float c = fmaf(fv, cc2[r], iv * gv);
        cc2[r] = c;
        const float th = fmaf(-2.f, SG(c * TWOL2E), 1.f);
        const float hv = ov * th;
        s_h2[t & 1][lg * 4 + r][2 * ln + w] = (f16)hv;
        if (t == TT - 1)
          out[which * 8192 + (rowbase + lg * 4 + r) * 32 + 2 * ln + w] = hv;
      }
    }
    __syncthreads();
  }
}

extern "C" void kernel_launch(void* const* d_in, const int* in_sizes, int n_in,
                              void* d_out, int out_size, void* d_ws, size_t ws_size,
                              hipStream_t stream) {
  const float* x1   = (const float*)d_in[0];
  const float* x2   = (const float*)d_in[1];
  const float* Wih1 = (const float*)d_in[2];
  const float* Whh1 = (const float*)d_in[3];
  const float* bih1 = (const float*)d_in[4];
  const float* bhh1 = (const float*)d_in[5];
  const float* Wih2 = (const float*)d_in[6];
  const float* Whh2 = (const float*)d_in[7];
  const float* bih2 = (const float*)d_in[8];
  const float* bhh2 = (const float*)d_in[9];
  float* out = (float*)d_out;

  f16*   wsf = (f16*)d_ws;                        // 88 tiles * 1 KB
  float* wsb = (float*)((char*)d_ws + 90112);     // 384 scaled biases

  lstm2_v12_prep<<<dim3(89), dim3(64), 0, stream>>>(
      Wih1, Whh1, Wih2, Whh2, bih1, bhh1, bih2, bhh2, wsf, wsb);
  lstm2_v12_main<<<dim3(32), dim3(256), 0, stream>>>(
      x1, x2, wsf, wsb, out);
}